// Round 16
// baseline (163.828 us; speedup 1.0000x reference)
//
#include <hip/hip_runtime.h>
#include <hip/hip_bf16.h>

#define NB 16384
#define NH 50

typedef __attribute__((ext_vector_type(4))) float        f32x4;
typedef __attribute__((ext_vector_type(8))) short        s16x8;
typedef __attribute__((ext_vector_type(4))) unsigned int u32x4;

// ws layout (floats):
//   bfrag (u32) : [0, 8192)        32 KB  — W hi/lo bf16 MFMA fragments
//   user_vec    : [6400000, +1M)   4.2 MB
//   target_rep  : [7448576, +1M)   4.2 MB

__device__ __forceinline__ unsigned rne16(float x) {
  unsigned u = __float_as_uint(x);
  return (u + 0x7FFFu + ((u >> 16) & 1u)) >> 16;
}

__device__ __forceinline__ unsigned pk_bf16(float r0, float r1) {
  __hip_bfloat162 h = __float22bfloat162_rn(make_float2(r0, r1));  // v_cvt_pk_bf16_f32
  unsigned u;
  __builtin_memcpy(&u, &h, 4);
  return u;
}

// trunc-hi split: x = hi + r exactly (hi = upper-16 bits, bf16-representable);
// lo = rne(r).
__device__ __forceinline__ void cvt8t(const f32x4 a, const f32x4 b, u32x4& hi, u32x4& lo) {
  unsigned ha[8]; float r[8];
#pragma unroll
  for (int i = 0; i < 4; ++i) {
    const unsigned ua = __float_as_uint(a[i]) & 0xFFFF0000u;
    ha[i] = ua; r[i] = a[i] - __uint_as_float(ua);
  }
#pragma unroll
  for (int i = 0; i < 4; ++i) {
    const unsigned ub = __float_as_uint(b[i]) & 0xFFFF0000u;
    ha[4 + i] = ub; r[4 + i] = b[i] - __uint_as_float(ub);
  }
#pragma unroll
  for (int p = 0; p < 4; ++p) {
    hi[p] = ha[2 * p + 1] | (ha[2 * p] >> 16);   // elem 2p -> low16, 2p+1 -> high16
    lo[p] = pk_bf16(r[2 * p], r[2 * p + 1]);
  }
}

// ---------------- kernel W: build bf16 hi/lo B-fragments of fusion_w ----------------
// frag set f = (ks<<3)|(nt<<1)|sp ; lane l ; dword j : B[ks*32+(l>>4)*8+2j(+1)][nt*16+(l&15)]
__global__ __launch_bounds__(256) void wprep_k(const float* __restrict__ fw,
                                               unsigned* __restrict__ bfrag) {
  const int d = blockIdx.x * 256 + threadIdx.x;   // 0..8191
  const int j = d & 3, l = (d >> 2) & 63, f = d >> 8;
  const int sp = f & 1, nt = (f >> 1) & 3, ks = f >> 3;
  const int n  = nt * 16 + (l & 15);
  const int k0 = ks * 32 + (l >> 4) * 8 + 2 * j;
  const float w0 = fw[k0 * 64 + n], w1 = fw[(k0 + 1) * 64 + n];
  const unsigned h0 = rne16(w0), h1 = rne16(w1);
  unsigned dw;
  if (sp == 0) dw = h0 | (h1 << 16);
  else {
    const float r0 = w0 - __uint_as_float(h0 << 16);
    const float r1 = w1 - __uint_as_float(h1 << 16);
    dw = rne16(r0) | (rne16(r1) << 16);
  }
  bfrag[d] = dw;
}

// ---------------- kernel B: MFMA item-rep + pooling ----------------
// B in LDS, 3 waves/SIMD (the measured spill-free optimum), sched_barrier per
// iteration. NEW: both batches share one B-sweep per m-tile -> LDS reads
// halved (32 ds_read_b128 serve 96 MFMAs instead of 48).
__global__ __launch_bounds__(256, 3) void pool_mfma_k(
    const int* __restrict__ hidx, const float* __restrict__ hfeat,
    const float* __restrict__ hrat, const int* __restrict__ tidx,
    const float* __restrict__ tfeat, const float* __restrict__ table,
    const float* __restrict__ fb, const unsigned* __restrict__ bfrag,
    float* __restrict__ user_vec, float* __restrict__ target_rep)
{
  __shared__ u32x4 sB[2048];   // 32 KB: frag f in 0..31, lane l: sB[f*64 + l]
  const int tid = threadIdx.x;
  {
    const u32x4* src = (const u32x4*)bfrag;
#pragma unroll
    for (int k = 0; k < 8; ++k) sB[tid + k * 256] = src[tid + k * 256];
  }

  const int l  = tid & 63;
  const int wv = tid >> 6;
  const int wave = (blockIdx.x << 2) + wv;          // 0..8191
  const int lm = l & 15, lg = l >> 4;
  const int b0 = wave, b1 = wave + 8192;

  // coalesced headers for BOTH batches
  const int r_l = (l < NH) ? l : (NH - 1);
  int idxv0 = hidx[(size_t)b0 * NH + r_l];
  int idxv1 = hidx[(size_t)b1 * NH + r_l];
  float rat0 = (l < NH) ? (hrat[(size_t)b0 * NH + l] - 3.0f) : 0.f;
  float rat1 = (l < NH) ? (hrat[(size_t)b1 * NH + l] - 3.0f) : 0.f;
  if (l == NH) { idxv0 = tidx[b0]; idxv1 = tidx[b1]; }   // lane 50 carries target

  float bias[4];
#pragma unroll
  for (int nt = 0; nt < 4; ++nt) bias[nt] = fb[nt * 16 + lm];

  __syncthreads();   // sB ready

  // load A-rows of 16x128 sub-tile (batch bb, m) into q[8]
  auto load_tile = [&](int bb, int mi, int m, f32x4* q) {
    const int r   = m * 16 + lm;
    const int sel = (r <= NH) ? r : (NH - 1);
    const int idxm = __shfl(mi, sel, 64);
    const float* fp = (r < NH) ? (hfeat + ((size_t)bb * NH + r) * 64)
                    : (r == NH) ? (tfeat + (size_t)bb * 64)
                                : (hfeat + ((size_t)bb * NH + (NH - 1)) * 64);
    const float* ep = table + (size_t)idxm * 64;
    q[0] = *(const f32x4*)(ep + lg * 8);
    q[1] = *(const f32x4*)(ep + lg * 8 + 4);
    q[2] = *(const f32x4*)(ep + 32 + lg * 8);
    q[3] = *(const f32x4*)(ep + 32 + lg * 8 + 4);
    q[4] = *(const f32x4*)(fp + lg * 8);
    q[5] = *(const f32x4*)(fp + lg * 8 + 4);
    q[6] = *(const f32x4*)(fp + 32 + lg * 8);
    q[7] = *(const f32x4*)(fp + 32 + lg * 8 + 4);
  };

  float uacc0[4] = {0.f, 0.f, 0.f, 0.f}, uacc1[4] = {0.f, 0.f, 0.f, 0.f};
  float trep0[4] = {0.f, 0.f, 0.f, 0.f}, trep1[4] = {0.f, 0.f, 0.f, 0.f};

#pragma unroll
  for (int m = 0; m < 4; ++m) {
    // --- load + convert both batches' m-tiles (issue all 16 loads first) ---
    f32x4 q0[8], q1[8];
    load_tile(b0, idxv0, m, q0);
    load_tile(b1, idxv1, m, q1);

    u32x4 ahi0[4], alo0[4], ahi1[4], alo1[4];
    cvt8t(q0[0], q0[1], ahi0[0], alo0[0]);
    cvt8t(q0[2], q0[3], ahi0[1], alo0[1]);
    cvt8t(q0[4], q0[5], ahi0[2], alo0[2]);
    cvt8t(q0[6], q0[7], ahi0[3], alo0[3]);
    cvt8t(q1[0], q1[1], ahi1[0], alo1[0]);
    cvt8t(q1[2], q1[3], ahi1[1], alo1[1]);
    cvt8t(q1[4], q1[5], ahi1[2], alo1[2]);
    cvt8t(q1[6], q1[7], ahi1[3], alo1[3]);

    f32x4 acc0[4], acc1[4];
#pragma unroll
    for (int nt = 0; nt < 4; ++nt) {
      const float bv = bias[nt];
      acc0[nt] = (f32x4){bv, bv, bv, bv};
      acc1[nt] = (f32x4){bv, bv, bv, bv};
    }

    // --- shared B-sweep: each bh/bl read once, feeds both batches ---
#pragma unroll
    for (int ks = 0; ks < 4; ++ks) {
      const s16x8 ah0 = __builtin_bit_cast(s16x8, ahi0[ks]);
      const s16x8 al0 = __builtin_bit_cast(s16x8, alo0[ks]);
      const s16x8 ah1 = __builtin_bit_cast(s16x8, ahi1[ks]);
      const s16x8 al1 = __builtin_bit_cast(s16x8, alo1[ks]);
#pragma unroll
      for (int nt = 0; nt < 4; ++nt) {
        const s16x8 bh = __builtin_bit_cast(s16x8, sB[((ks * 8 + nt * 2 + 0) * 64) + l]);
        const s16x8 bl = __builtin_bit_cast(s16x8, sB[((ks * 8 + nt * 2 + 1) * 64) + l]);
        acc0[nt] = __builtin_amdgcn_mfma_f32_16x16x32_bf16(ah0, bh, acc0[nt], 0, 0, 0);
        acc1[nt] = __builtin_amdgcn_mfma_f32_16x16x32_bf16(ah1, bh, acc1[nt], 0, 0, 0);
        acc0[nt] = __builtin_amdgcn_mfma_f32_16x16x32_bf16(al0, bh, acc0[nt], 0, 0, 0);
        acc1[nt] = __builtin_amdgcn_mfma_f32_16x16x32_bf16(al1, bh, acc1[nt], 0, 0, 0);
        acc0[nt] = __builtin_amdgcn_mfma_f32_16x16x32_bf16(ah0, bl, acc0[nt], 0, 0, 0);
        acc1[nt] = __builtin_amdgcn_mfma_f32_16x16x32_bf16(ah1, bl, acc1[nt], 0, 0, 0);
      }
    }

    // --- epilogues: relu + weighted pooling ; C layout: col=lm+16nt, row=m*16+lg*4+e
#pragma unroll
    for (int e = 0; e < 4; ++e) {
      const int rr = m * 16 + lg * 4 + e;
      const float w0 = __shfl(rat0, rr, 64);
      const float w1 = __shfl(rat1, rr, 64);
#pragma unroll
      for (int nt = 0; nt < 4; ++nt) {
        const float rv0 = fmaxf(acc0[nt][e], 0.f);
        const float rv1 = fmaxf(acc1[nt][e], 0.f);
        uacc0[nt] = fmaf(w0, rv0, uacc0[nt]);
        uacc1[nt] = fmaf(w1, rv1, uacc1[nt]);
        if (m == 3 && e == 2) { trep0[nt] = rv0; trep1[nt] = rv1; }
      }
    }

    __builtin_amdgcn_sched_barrier(0);
  }

  // --- finalize both batches ---
  {
    float den0 = fabsf(rat0), den1 = fabsf(rat1);
#pragma unroll
    for (int s = 32; s >= 1; s >>= 1) {
      den0 += __shfl_xor(den0, s, 64);
      den1 += __shfl_xor(den1, s, 64);
    }
#pragma unroll
    for (int nt = 0; nt < 4; ++nt) {
      uacc0[nt] += __shfl_xor(uacc0[nt], 16, 64);
      uacc0[nt] += __shfl_xor(uacc0[nt], 32, 64);
      uacc1[nt] += __shfl_xor(uacc1[nt], 16, 64);
      uacc1[nt] += __shfl_xor(uacc1[nt], 32, 64);
    }
    const float d0 = den0 + 1e-8f, d1 = den1 + 1e-8f;
    const float u0 = (lg == 0) ? uacc0[0] : (lg == 1) ? uacc0[1]
                   : (lg == 2) ? uacc0[2] : uacc0[3];
    const float u1 = (lg == 0) ? uacc1[0] : (lg == 1) ? uacc1[1]
                   : (lg == 2) ? uacc1[2] : uacc1[3];
    user_vec[(size_t)b0 * 64 + l] = u0 / d0;
    user_vec[(size_t)b1 * 64 + l] = u1 / d1;
    if (l < 16) {
      float* tp0 = target_rep + (size_t)b0 * 64 + l;
      float* tp1 = target_rep + (size_t)b1 * 64 + l;
      tp0[0] = trep0[0]; tp0[16] = trep0[1]; tp0[32] = trep0[2]; tp0[48] = trep0[3];
      tp1[0] = trep1[0]; tp1[16] = trep1[1]; tp1[32] = trep1[2]; tp1[48] = trep1[3];
    }
  }
}

// ---------------- kernel C: rating MLP ----------------
__global__ __launch_bounds__(256) void mlp_k(
    const float* __restrict__ user_vec, const float* __restrict__ target_rep,
    const float* __restrict__ w1, const float* __restrict__ b1,
    const float* __restrict__ w2, const float* __restrict__ b2,
    const float* __restrict__ w3, const float* __restrict__ b3,
    float* __restrict__ out)
{
  __shared__ alignas(16) float s_w1[128 * 64];  // 32 KB
  __shared__ alignas(16) float s_w2[64 * 32];   //  8 KB
  __shared__ float s_w3[32];
  __shared__ alignas(16) float s_x[4][128];
  __shared__ alignas(16) float s_h1[4][64];
  const int tid = threadIdx.x;
  for (int i = tid; i < 128 * 64; i += 256) s_w1[i] = w1[i];
  for (int i = tid; i < 64 * 32;  i += 256) s_w2[i] = w2[i];
  if (tid < 32) s_w3[tid] = w3[tid];
  __syncthreads();

  const int t  = tid & 63;
  const int wv = tid >> 6;
  const int nwaves = gridDim.x << 2;
  const float b1t = b1[t];
  const float bb3 = b3[0];
  const int n2 = t & 31;
  const float b2n = b2[n2];
  for (int b = (blockIdx.x << 2) + wv; b < NB; b += nwaves) {
    s_x[wv][t]      = user_vec[(size_t)b * 64 + t];
    s_x[wv][64 + t] = target_rep[(size_t)b * 64 + t];
    float a0 = b1t, a1 = 0.f, a2 = 0.f, a3 = 0.f;
#pragma unroll
    for (int k4 = 0; k4 < 32; ++k4) {
      float4 x = *reinterpret_cast<const float4*>(&s_x[wv][k4 * 4]);
      a0 = fmaf(x.x, s_w1[(4 * k4 + 0) * 64 + t], a0);
      a1 = fmaf(x.y, s_w1[(4 * k4 + 1) * 64 + t], a1);
      a2 = fmaf(x.z, s_w1[(4 * k4 + 2) * 64 + t], a2);
      a3 = fmaf(x.w, s_w1[(4 * k4 + 3) * 64 + t], a3);
    }
    s_h1[wv][t] = fmaxf((a0 + a1) + (a2 + a3), 0.f);
    float c0 = b2n, c1 = 0.f, c2 = 0.f, c3 = 0.f;
#pragma unroll
    for (int k4 = 0; k4 < 16; ++k4) {
      float4 x = *reinterpret_cast<const float4*>(&s_h1[wv][k4 * 4]);
      c0 = fmaf(x.x, s_w2[(4 * k4 + 0) * 32 + n2], c0);
      c1 = fmaf(x.y, s_w2[(4 * k4 + 1) * 32 + n2], c1);
      c2 = fmaf(x.z, s_w2[(4 * k4 + 2) * 32 + n2], c2);
      c3 = fmaf(x.w, s_w2[(4 * k4 + 3) * 32 + n2], c3);
    }
    const float h2 = fmaxf((c0 + c1) + (c2 + c3), 0.f);
    float p = (t < 32) ? h2 * s_w3[n2] : 0.f;
#pragma unroll
    for (int m = 32; m >= 1; m >>= 1) p += __shfl_xor(p, m, 64);
    if (t == 0) out[b] = p + bb3;
  }
}

extern "C" void kernel_launch(void* const* d_in, const int* in_sizes, int n_in,
                              void* d_out, int out_size, void* d_ws, size_t ws_size,
                              hipStream_t stream) {
  const int*   hidx  = (const int*)  d_in[0];
  const float* hfeat = (const float*)d_in[1];
  const float* hrat  = (const float*)d_in[2];
  const int*   tidx  = (const int*)  d_in[3];
  const float* tfeat = (const float*)d_in[4];
  const float* table = (const float*)d_in[5];
  const float* fw    = (const float*)d_in[6];
  const float* fb    = (const float*)d_in[7];
  const float* w1    = (const float*)d_in[8];
  const float* b1    = (const float*)d_in[9];
  const float* w2    = (const float*)d_in[10];
  const float* b2    = (const float*)d_in[11];
  const float* w3    = (const float*)d_in[12];
  const float* b3    = (const float*)d_in[13];
  float* out = (float*)d_out;
  float* ws  = (float*)d_ws;
  unsigned* bfrag   = (unsigned*)ws;      // 8192 dwords
  float* user_vec   = ws + 6400000;
  float* target_rep = ws + 7448576;

  hipLaunchKernelGGL(wprep_k, dim3(32), dim3(256), 0, stream, fw, bfrag);
  hipLaunchKernelGGL(pool_mfma_k, dim3(2048), dim3(256), 0, stream,
                     hidx, hfeat, hrat, tidx, tfeat, table, fb, bfrag,
                     user_vec, target_rep);
  hipLaunchKernelGGL(mlp_k, dim3(512), dim3(256), 0, stream,
                     user_vec, target_rep, w1, b1, w2, b2, w3, b3, out);
}

// Round 17
// 112.885 us; speedup vs baseline: 1.4513x; 1.4513x over previous
//
#include <hip/hip_runtime.h>
#include <hip/hip_bf16.h>

#define NB 16384
#define NH 50
#define NITEMS 100000

typedef __attribute__((ext_vector_type(4))) float        f32x4;
typedef __attribute__((ext_vector_type(8))) short        s16x8;
typedef __attribute__((ext_vector_type(4))) unsigned int u32x4;

// ws layout:
//   bfrag  (u32)  : [0, 8192)                 32 KB  — W hi/lo bf16 fragments
//   table_hi (u32): [16384, 3216384)          12.8 MB — emb hi-packed
//   table_lo (u32): [3216384, 6416384)        12.8 MB — emb lo-packed
//   user_vec  (f32): [8000000, +1048576)
//   target_rep(f32): [9048576, +1048576)

__device__ __forceinline__ unsigned rne16(float x) {
  unsigned u = __float_as_uint(x);
  return (u + 0x7FFFu + ((u >> 16) & 1u)) >> 16;
}

__device__ __forceinline__ unsigned pk_bf16(float r0, float r1) {
  __hip_bfloat162 h = __float22bfloat162_rn(make_float2(r0, r1));  // v_cvt_pk_bf16_f32
  unsigned u;
  __builtin_memcpy(&u, &h, 4);
  return u;
}

// trunc-hi split: x = hi + r exactly; lo = rne(r). Same math as tprep_k.
__device__ __forceinline__ void cvt8t(const f32x4 a, const f32x4 b, u32x4& hi, u32x4& lo) {
  unsigned ha[8]; float r[8];
#pragma unroll
  for (int i = 0; i < 4; ++i) {
    const unsigned ua = __float_as_uint(a[i]) & 0xFFFF0000u;
    ha[i] = ua; r[i] = a[i] - __uint_as_float(ua);
  }
#pragma unroll
  for (int i = 0; i < 4; ++i) {
    const unsigned ub = __float_as_uint(b[i]) & 0xFFFF0000u;
    ha[4 + i] = ub; r[4 + i] = b[i] - __uint_as_float(ub);
  }
#pragma unroll
  for (int p = 0; p < 4; ++p) {
    hi[p] = ha[2 * p + 1] | (ha[2 * p] >> 16);   // elem 2p -> low16, 2p+1 -> high16
    lo[p] = pk_bf16(r[2 * p], r[2 * p + 1]);
  }
}

// ---------------- kernel W: build bf16 hi/lo B-fragments of fusion_w ----------------
__global__ __launch_bounds__(256) void wprep_k(const float* __restrict__ fw,
                                               unsigned* __restrict__ bfrag) {
  const int d = blockIdx.x * 256 + threadIdx.x;   // 0..8191
  const int j = d & 3, l = (d >> 2) & 63, f = d >> 8;
  const int sp = f & 1, nt = (f >> 1) & 3, ks = f >> 3;
  const int n  = nt * 16 + (l & 15);
  const int k0 = ks * 32 + (l >> 4) * 8 + 2 * j;
  const float w0 = fw[k0 * 64 + n], w1 = fw[(k0 + 1) * 64 + n];
  const unsigned h0 = rne16(w0), h1 = rne16(w1);
  unsigned dw;
  if (sp == 0) dw = h0 | (h1 << 16);
  else {
    const float r0 = w0 - __uint_as_float(h0 << 16);
    const float r1 = w1 - __uint_as_float(h1 << 16);
    dw = rne16(r0) | (rne16(r1) << 16);
  }
  bfrag[d] = dw;
}

// ---------------- kernel T: pre-pack embed_table into hi/lo bf16 pairs ----------------
// thi[item*32+k] = pack(e[2k],e[2k+1]) trunc-hi ; tlo = rne residual (same as cvt8t)
__global__ __launch_bounds__(256) void tprep_k(const float* __restrict__ table,
                                               unsigned* __restrict__ thi,
                                               unsigned* __restrict__ tlo) {
  const int d = blockIdx.x * 256 + threadIdx.x;   // pair index
  if (d >= NITEMS * 32) return;
  const float2 e = ((const float2*)table)[d];
  const unsigned u0 = __float_as_uint(e.x) & 0xFFFF0000u;
  const unsigned u1 = __float_as_uint(e.y) & 0xFFFF0000u;
  thi[d] = u1 | (u0 >> 16);
  const float r0 = e.x - __uint_as_float(u0);
  const float r1 = e.y - __uint_as_float(u1);
  tlo[d] = pk_bf16(r0, r1);
}

// ---------------- kernel B: MFMA item-rep + pooling ----------------
// R14 structure (B in LDS, 3 waves/SIMD, 1-deep prefetch, sched_barrier/tile);
// emb half now loads MFMA-ready packed fragments (no cvt, -16 transient regs).
__global__ __launch_bounds__(256, 3) void pool_mfma_k(
    const int* __restrict__ hidx, const float* __restrict__ hfeat,
    const float* __restrict__ hrat, const int* __restrict__ tidx,
    const float* __restrict__ tfeat,
    const unsigned* __restrict__ thi, const unsigned* __restrict__ tlo,
    const float* __restrict__ fb, const unsigned* __restrict__ bfrag,
    float* __restrict__ user_vec, float* __restrict__ target_rep)
{
  __shared__ u32x4 sB[2048];   // 32 KB: frag f in 0..31, lane l: sB[f*64 + l]
  const int tid = threadIdx.x;
  {
    const u32x4* src = (const u32x4*)bfrag;
#pragma unroll
    for (int k = 0; k < 8; ++k) sB[tid + k * 256] = src[tid + k * 256];
  }

  const int l  = tid & 63;
  const int wv = tid >> 6;
  const int wave = (blockIdx.x << 2) + wv;          // 0..8191
  const int lm = l & 15, lg = l >> 4;
  const int b0 = wave, b1 = wave + 8192;

  // coalesced headers for BOTH batches
  const int r_l = (l < NH) ? l : (NH - 1);
  int idxv0 = hidx[(size_t)b0 * NH + r_l];
  int idxv1 = hidx[(size_t)b1 * NH + r_l];
  float rat0 = (l < NH) ? (hrat[(size_t)b0 * NH + l] - 3.0f) : 0.f;
  float rat1 = (l < NH) ? (hrat[(size_t)b1 * NH + l] - 3.0f) : 0.f;
  if (l == NH) { idxv0 = tidx[b0]; idxv1 = tidx[b1]; }   // lane 50 carries target

  float bias[4];
#pragma unroll
  for (int nt = 0; nt < 4; ++nt) bias[nt] = fb[nt * 16 + lm];

  __syncthreads();   // sB ready

  // tile i (i = rep*4 + m): emb fragments (packed) + feat rows (fp32)
  auto load_tile = [&](int i, u32x4* qe, f32x4* qf) {
    const int rep = i >> 2, m = i & 3;
    const int bb  = rep ? b1 : b0;
    const int mi  = rep ? idxv1 : idxv0;
    const int r   = m * 16 + lm;
    const int sel = (r <= NH) ? r : (NH - 1);
    const int idxm = __shfl(mi, sel, 64);
    const float* fp = (r < NH) ? (hfeat + ((size_t)bb * NH + r) * 64)
                    : (r == NH) ? (tfeat + (size_t)bb * 64)
                                : (hfeat + ((size_t)bb * NH + (NH - 1)) * 64);
    const unsigned* eh = thi + (size_t)idxm * 32;
    const unsigned* el = tlo + (size_t)idxm * 32;
    qe[0] = *(const u32x4*)(eh + lg * 4);        // ahi[0]
    qe[1] = *(const u32x4*)(eh + 16 + lg * 4);   // ahi[1]
    qe[2] = *(const u32x4*)(el + lg * 4);        // alo[0]
    qe[3] = *(const u32x4*)(el + 16 + lg * 4);   // alo[1]
    qf[0] = *(const f32x4*)(fp + lg * 8);
    qf[1] = *(const f32x4*)(fp + lg * 8 + 4);
    qf[2] = *(const f32x4*)(fp + 32 + lg * 8);
    qf[3] = *(const f32x4*)(fp + 32 + lg * 8 + 4);
  };

  u32x4 qeA[4], qeB[4];
  f32x4 qfA[4], qfB[4];
  load_tile(0, qeA, qfA);

  float uacc[4] = {0.f, 0.f, 0.f, 0.f};
  float trep[4] = {0.f, 0.f, 0.f, 0.f};

#pragma unroll
  for (int i = 0; i < 8; ++i) {
    const int rep = i >> 2, m = i & 3;
    u32x4* qec = (i & 1) ? qeB : qeA;
    f32x4* qfc = (i & 1) ? qfB : qfA;
    u32x4* qen = (i & 1) ? qeA : qeB;
    f32x4* qfn = (i & 1) ? qfA : qfB;

    // emb fragments are load-ready; only feat half needs cvt
    u32x4 ahi[4], alo[4];
    ahi[0] = qec[0]; ahi[1] = qec[1];
    alo[0] = qec[2]; alo[1] = qec[3];
    cvt8t(qfc[0], qfc[1], ahi[2], alo[2]);
    cvt8t(qfc[2], qfc[3], ahi[3], alo[3]);

    // prefetch next tile; its s_waitcnt lands at tile i+1's cvt
    if (i < 7) load_tile(i + 1, qen, qfn);

    f32x4 acc[4];
#pragma unroll
    for (int nt = 0; nt < 4; ++nt) {
      const float bv = bias[nt];
      acc[nt] = (f32x4){bv, bv, bv, bv};
    }
#pragma unroll
    for (int ks = 0; ks < 4; ++ks) {
      const s16x8 ah = __builtin_bit_cast(s16x8, ahi[ks]);
      const s16x8 al = __builtin_bit_cast(s16x8, alo[ks]);
#pragma unroll
      for (int nt = 0; nt < 4; ++nt) {
        const s16x8 bh = __builtin_bit_cast(s16x8, sB[((ks * 8 + nt * 2 + 0) * 64) + l]);
        const s16x8 bl = __builtin_bit_cast(s16x8, sB[((ks * 8 + nt * 2 + 1) * 64) + l]);
        acc[nt] = __builtin_amdgcn_mfma_f32_16x16x32_bf16(ah, bh, acc[nt], 0, 0, 0);
        acc[nt] = __builtin_amdgcn_mfma_f32_16x16x32_bf16(al, bh, acc[nt], 0, 0, 0);
        acc[nt] = __builtin_amdgcn_mfma_f32_16x16x32_bf16(ah, bl, acc[nt], 0, 0, 0);
      }
    }

    // epilogue: relu + weighted pooling ; C layout: col=lm+16nt, row=m*16+lg*4+e
    const float rw_all = rep ? rat1 : rat0;
#pragma unroll
    for (int e = 0; e < 4; ++e) {
      const int rr = m * 16 + lg * 4 + e;
      const float w = __shfl(rw_all, rr, 64);
#pragma unroll
      for (int nt = 0; nt < 4; ++nt) {
        const float repv = fmaxf(acc[nt][e], 0.f);
        uacc[nt] = fmaf(w, repv, uacc[nt]);
        if (m == 3 && e == 2) trep[nt] = repv;   // row 50 = target (valid on lg==0)
      }
    }

    if (m == 3) {
      // finalize this batch
      const int bb = rep ? b1 : b0;
      float den = fabsf(rw_all);
#pragma unroll
      for (int s = 32; s >= 1; s >>= 1) den += __shfl_xor(den, s, 64);
#pragma unroll
      for (int nt = 0; nt < 4; ++nt) {
        uacc[nt] += __shfl_xor(uacc[nt], 16, 64);
        uacc[nt] += __shfl_xor(uacc[nt], 32, 64);
      }
      const float dinv = den + 1e-8f;
      const float usel = (lg == 0) ? uacc[0] : (lg == 1) ? uacc[1]
                       : (lg == 2) ? uacc[2] : uacc[3];
      user_vec[(size_t)bb * 64 + l] = usel / dinv;
      if (l < 16) {
        float* tp = target_rep + (size_t)bb * 64 + l;
        tp[0]  = trep[0];
        tp[16] = trep[1];
        tp[32] = trep[2];
        tp[48] = trep[3];
      }
#pragma unroll
      for (int nt = 0; nt < 4; ++nt) { uacc[nt] = 0.f; trep[nt] = 0.f; }
    }

    // cap scheduler pressure: no cross-tile hoisting bulges
    __builtin_amdgcn_sched_barrier(0);
  }
}

// ---------------- kernel C: rating MLP ----------------
__global__ __launch_bounds__(256) void mlp_k(
    const float* __restrict__ user_vec, const float* __restrict__ target_rep,
    const float* __restrict__ w1, const float* __restrict__ b1,
    const float* __restrict__ w2, const float* __restrict__ b2,
    const float* __restrict__ w3, const float* __restrict__ b3,
    float* __restrict__ out)
{
  __shared__ alignas(16) float s_w1[128 * 64];  // 32 KB
  __shared__ alignas(16) float s_w2[64 * 32];   //  8 KB
  __shared__ float s_w3[32];
  __shared__ alignas(16) float s_x[4][128];
  __shared__ alignas(16) float s_h1[4][64];
  const int tid = threadIdx.x;
  for (int i = tid; i < 128 * 64; i += 256) s_w1[i] = w1[i];
  for (int i = tid; i < 64 * 32;  i += 256) s_w2[i] = w2[i];
  if (tid < 32) s_w3[tid] = w3[tid];
  __syncthreads();

  const int t  = tid & 63;
  const int wv = tid >> 6;
  const int nwaves = gridDim.x << 2;
  const float b1t = b1[t];
  const float bb3 = b3[0];
  const int n2 = t & 31;
  const float b2n = b2[n2];
  for (int b = (blockIdx.x << 2) + wv; b < NB; b += nwaves) {
    s_x[wv][t]      = user_vec[(size_t)b * 64 + t];
    s_x[wv][64 + t] = target_rep[(size_t)b * 64 + t];
    float a0 = b1t, a1 = 0.f, a2 = 0.f, a3 = 0.f;
#pragma unroll
    for (int k4 = 0; k4 < 32; ++k4) {
      float4 x = *reinterpret_cast<const float4*>(&s_x[wv][k4 * 4]);
      a0 = fmaf(x.x, s_w1[(4 * k4 + 0) * 64 + t], a0);
      a1 = fmaf(x.y, s_w1[(4 * k4 + 1) * 64 + t], a1);
      a2 = fmaf(x.z, s_w1[(4 * k4 + 2) * 64 + t], a2);
      a3 = fmaf(x.w, s_w1[(4 * k4 + 3) * 64 + t], a3);
    }
    s_h1[wv][t] = fmaxf((a0 + a1) + (a2 + a3), 0.f);
    float c0 = b2n, c1 = 0.f, c2 = 0.f, c3 = 0.f;
#pragma unroll
    for (int k4 = 0; k4 < 16; ++k4) {
      float4 x = *reinterpret_cast<const float4*>(&s_h1[wv][k4 * 4]);
      c0 = fmaf(x.x, s_w2[(4 * k4 + 0) * 32 + n2], c0);
      c1 = fmaf(x.y, s_w2[(4 * k4 + 1) * 32 + n2], c1);
      c2 = fmaf(x.z, s_w2[(4 * k4 + 2) * 32 + n2], c2);
      c3 = fmaf(x.w, s_w2[(4 * k4 + 3) * 32 + n2], c3);
    }
    const float h2 = fmaxf((c0 + c1) + (c2 + c3), 0.f);
    float p = (t < 32) ? h2 * s_w3[n2] : 0.f;
#pragma unroll
    for (int m = 32; m >= 1; m >>= 1) p += __shfl_xor(p, m, 64);
    if (t == 0) out[b] = p + bb3;
  }
}

extern "C" void kernel_launch(void* const* d_in, const int* in_sizes, int n_in,
                              void* d_out, int out_size, void* d_ws, size_t ws_size,
                              hipStream_t stream) {
  const int*   hidx  = (const int*)  d_in[0];
  const float* hfeat = (const float*)d_in[1];
  const float* hrat  = (const float*)d_in[2];
  const int*   tidx  = (const int*)  d_in[3];
  const float* tfeat = (const float*)d_in[4];
  const float* table = (const float*)d_in[5];
  const float* fw    = (const float*)d_in[6];
  const float* fb    = (const float*)d_in[7];
  const float* w1    = (const float*)d_in[8];
  const float* b1    = (const float*)d_in[9];
  const float* w2    = (const float*)d_in[10];
  const float* b2    = (const float*)d_in[11];
  const float* w3    = (const float*)d_in[12];
  const float* b3    = (const float*)d_in[13];
  float* out = (float*)d_out;
  float* ws  = (float*)d_ws;
  unsigned* bfrag    = (unsigned*)ws;             // [0, 8192)
  unsigned* table_hi = (unsigned*)ws + 16384;     // 3.2M u32
  unsigned* table_lo = (unsigned*)ws + 3216384;   // 3.2M u32
  float* user_vec    = ws + 8000000;
  float* target_rep  = ws + 9048576;

  hipLaunchKernelGGL(wprep_k, dim3(32), dim3(256), 0, stream, fw, bfrag);
  hipLaunchKernelGGL(tprep_k, dim3(12500), dim3(256), 0, stream, table, table_hi, table_lo);
  hipLaunchKernelGGL(pool_mfma_k, dim3(2048), dim3(256), 0, stream,
                     hidx, hfeat, hrat, tidx, tfeat, table_hi, table_lo, fb, bfrag,
                     user_vec, target_rep);
  hipLaunchKernelGGL(mlp_k, dim3(512), dim3(256), 0, stream,
                     user_vec, target_rep, w1, b1, w2, b2, w3, b3, out);
}

// Round 18
// 111.607 us; speedup vs baseline: 1.4679x; 1.0115x over previous
//
#include <hip/hip_runtime.h>
#include <hip/hip_bf16.h>

#define NB 16384
#define NH 50
#define NITEMS 100000

typedef __attribute__((ext_vector_type(4))) float        f32x4;
typedef __attribute__((ext_vector_type(8))) short        s16x8;
typedef __attribute__((ext_vector_type(4))) unsigned int u32x4;

// ws layout:
//   bfrag (u32) : [0, 8192)           32 KB — W hi/lo bf16 fragments (ks0-1=emb, ks2-3=feat)
//   femb  (f32) : [16384, +6400000)   25.6 MB — embed_table @ W_emb (pre-activation partial)
//   user_vec  (f32): [8000000, +1048576)
//   target_rep(f32): [9048576, +1048576)

__device__ __forceinline__ unsigned rne16(float x) {
  unsigned u = __float_as_uint(x);
  return (u + 0x7FFFu + ((u >> 16) & 1u)) >> 16;
}

__device__ __forceinline__ unsigned pk_bf16(float r0, float r1) {
  __hip_bfloat162 h = __float22bfloat162_rn(make_float2(r0, r1));  // v_cvt_pk_bf16_f32
  unsigned u;
  __builtin_memcpy(&u, &h, 4);
  return u;
}

// trunc-hi split: x = hi + r exactly; lo = rne(r).
__device__ __forceinline__ void cvt8t(const f32x4 a, const f32x4 b, u32x4& hi, u32x4& lo) {
  unsigned ha[8]; float r[8];
#pragma unroll
  for (int i = 0; i < 4; ++i) {
    const unsigned ua = __float_as_uint(a[i]) & 0xFFFF0000u;
    ha[i] = ua; r[i] = a[i] - __uint_as_float(ua);
  }
#pragma unroll
  for (int i = 0; i < 4; ++i) {
    const unsigned ub = __float_as_uint(b[i]) & 0xFFFF0000u;
    ha[4 + i] = ub; r[4 + i] = b[i] - __uint_as_float(ub);
  }
#pragma unroll
  for (int p = 0; p < 4; ++p) {
    hi[p] = ha[2 * p + 1] | (ha[2 * p] >> 16);   // elem 2p -> low16, 2p+1 -> high16
    lo[p] = pk_bf16(r[2 * p], r[2 * p + 1]);
  }
}

// ---------------- kernel W: build bf16 hi/lo B-fragments of fusion_w ----------------
// frag f=(ks<<3)|(nt<<1)|sp ; lane l ; dword j : B[ks*32+(l>>4)*8+2j(+1)][nt*16+(l&15)]
__global__ __launch_bounds__(256) void wprep_k(const float* __restrict__ fw,
                                               unsigned* __restrict__ bfrag) {
  const int d = blockIdx.x * 256 + threadIdx.x;   // 0..8191
  const int j = d & 3, l = (d >> 2) & 63, f = d >> 8;
  const int sp = f & 1, nt = (f >> 1) & 3, ks = f >> 3;
  const int n  = nt * 16 + (l & 15);
  const int k0 = ks * 32 + (l >> 4) * 8 + 2 * j;
  const float w0 = fw[k0 * 64 + n], w1 = fw[(k0 + 1) * 64 + n];
  const unsigned h0 = rne16(w0), h1 = rne16(w1);
  unsigned dw;
  if (sp == 0) dw = h0 | (h1 << 16);
  else {
    const float r0 = w0 - __uint_as_float(h0 << 16);
    const float r1 = w1 - __uint_as_float(h1 << 16);
    dw = rne16(r0) | (rne16(r1) << 16);
  }
  bfrag[d] = dw;
}

// ---------------- kernel F: femb = embed_table @ W_emb (rows 0-63 of fusion_w) ----------
// One 16x64 output tile per wave; frags ks 0-1 from LDS. No bias, no relu.
__global__ __launch_bounds__(256) void femb_k(const float* __restrict__ table,
                                              const unsigned* __restrict__ bfrag,
                                              float* __restrict__ femb) {
  __shared__ u32x4 sB[1024];   // frags 0..15, 16 KB
  const int tid = threadIdx.x;
  {
    const u32x4* src = (const u32x4*)bfrag;
#pragma unroll
    for (int k = 0; k < 4; ++k) sB[tid + k * 256] = src[tid + k * 256];
  }
  const int l = tid & 63, wv = tid >> 6;
  const int w = blockIdx.x * 4 + wv;   // tile id, 16 rows each
  const int lm = l & 15, lg = l >> 4;
  __syncthreads();
  if (w >= NITEMS / 16) return;

  const float* tp = table + (size_t)(w * 16 + lm) * 64;
  f32x4 q0 = *(const f32x4*)(tp + lg * 8);
  f32x4 q1 = *(const f32x4*)(tp + lg * 8 + 4);
  f32x4 q2 = *(const f32x4*)(tp + 32 + lg * 8);
  f32x4 q3 = *(const f32x4*)(tp + 32 + lg * 8 + 4);
  u32x4 ahi[2], alo[2];
  cvt8t(q0, q1, ahi[0], alo[0]);
  cvt8t(q2, q3, ahi[1], alo[1]);

  f32x4 acc[4];
#pragma unroll
  for (int nt = 0; nt < 4; ++nt) acc[nt] = (f32x4){0.f, 0.f, 0.f, 0.f};
#pragma unroll
  for (int ks = 0; ks < 2; ++ks) {
    const s16x8 ah = __builtin_bit_cast(s16x8, ahi[ks]);
    const s16x8 al = __builtin_bit_cast(s16x8, alo[ks]);
#pragma unroll
    for (int nt = 0; nt < 4; ++nt) {
      const s16x8 bh = __builtin_bit_cast(s16x8, sB[((ks * 8 + nt * 2 + 0) * 64) + l]);
      const s16x8 bl = __builtin_bit_cast(s16x8, sB[((ks * 8 + nt * 2 + 1) * 64) + l]);
      acc[nt] = __builtin_amdgcn_mfma_f32_16x16x32_bf16(ah, bh, acc[nt], 0, 0, 0);
      acc[nt] = __builtin_amdgcn_mfma_f32_16x16x32_bf16(al, bh, acc[nt], 0, 0, 0);
      acc[nt] = __builtin_amdgcn_mfma_f32_16x16x32_bf16(ah, bl, acc[nt], 0, 0, 0);
    }
  }
  // C layout: col=lm+16nt, row = w*16 + lg*4 + e
#pragma unroll
  for (int e = 0; e < 4; ++e)
#pragma unroll
    for (int nt = 0; nt < 4; ++nt)
      femb[(size_t)(w * 16 + lg * 4 + e) * 64 + lm + 16 * nt] = acc[nt][e];
}

// ---------------- kernel B: MFMA item-rep (feat half, K=64) + femb gather + pooling ----
// R14 discipline: B in LDS, 3 waves/SIMD, 1-deep prefetch, sched_barrier/tile.
__global__ __launch_bounds__(256, 3) void pool_mfma_k(
    const int* __restrict__ hidx, const float* __restrict__ hfeat,
    const float* __restrict__ hrat, const int* __restrict__ tidx,
    const float* __restrict__ tfeat, const float* __restrict__ femb,
    const float* __restrict__ fb, const unsigned* __restrict__ bfrag,
    float* __restrict__ user_vec, float* __restrict__ target_rep)
{
  __shared__ u32x4 sB[1024];   // frags 16..31 (feat half), 16 KB
  const int tid = threadIdx.x;
  {
    const u32x4* src = ((const u32x4*)bfrag) + 1024;
#pragma unroll
    for (int k = 0; k < 4; ++k) sB[tid + k * 256] = src[tid + k * 256];
  }

  const int l  = tid & 63;
  const int wv = tid >> 6;
  const int wave = (blockIdx.x << 2) + wv;          // 0..8191
  const int lm = l & 15, lg = l >> 4;
  const int b0 = wave, b1 = wave + 8192;

  // coalesced headers for BOTH batches
  const int r_l = (l < NH) ? l : (NH - 1);
  int idxv0 = hidx[(size_t)b0 * NH + r_l];
  int idxv1 = hidx[(size_t)b1 * NH + r_l];
  float rat0 = (l < NH) ? (hrat[(size_t)b0 * NH + l] - 3.0f) : 0.f;
  float rat1 = (l < NH) ? (hrat[(size_t)b1 * NH + l] - 3.0f) : 0.f;
  if (l == NH) { idxv0 = tidx[b0]; idxv1 = tidx[b1]; }   // lane 50 carries target

  float bias[4];
#pragma unroll
  for (int nt = 0; nt < 4; ++nt) bias[nt] = fb[nt * 16 + lm];

  __syncthreads();   // sB ready

  // tile i (i = rep*4 + m): feat rows (A) + femb gathers (epilogue operand)
  auto load_tile = [&](int i, f32x4* qf, float* g) {
    const int rep = i >> 2, m = i & 3;
    const int bb  = rep ? b1 : b0;
    const int mi  = rep ? idxv1 : idxv0;
    const int r   = m * 16 + lm;
    const float* fp = (r < NH) ? (hfeat + ((size_t)bb * NH + r) * 64)
                    : (r == NH) ? (tfeat + (size_t)bb * 64)
                                : (hfeat + ((size_t)bb * NH + (NH - 1)) * 64);
    qf[0] = *(const f32x4*)(fp + lg * 8);
    qf[1] = *(const f32x4*)(fp + lg * 8 + 4);
    qf[2] = *(const f32x4*)(fp + 32 + lg * 8);
    qf[3] = *(const f32x4*)(fp + 32 + lg * 8 + 4);
    // femb gathers along C rows: rr = m*16 + lg*4 + e, cols lm+16nt
#pragma unroll
    for (int e = 0; e < 4; ++e) {
      const int rr = m * 16 + lg * 4 + e;
      const int se = (rr <= NH) ? rr : (NH - 1);
      const int ide = __shfl(mi, se, 64);
      const float* gp = femb + (size_t)ide * 64 + lm;
      g[e * 4 + 0] = gp[0];
      g[e * 4 + 1] = gp[16];
      g[e * 4 + 2] = gp[32];
      g[e * 4 + 3] = gp[48];
    }
  };

  f32x4 qfA[4], qfB[4];
  float gA[16], gB[16];
  load_tile(0, qfA, gA);

  float uacc[4] = {0.f, 0.f, 0.f, 0.f};
  float trep[4] = {0.f, 0.f, 0.f, 0.f};

#pragma unroll
  for (int i = 0; i < 8; ++i) {
    const int rep = i >> 2, m = i & 3;
    f32x4* qfc = (i & 1) ? qfB : qfA;
    float*  gc = (i & 1) ? gB  : gA;
    f32x4* qfn = (i & 1) ? qfA : qfB;
    float*  gn = (i & 1) ? gA  : gB;

    // convert current feat tile (qfc dies here)
    u32x4 ahi[2], alo[2];
    cvt8t(qfc[0], qfc[1], ahi[0], alo[0]);
    cvt8t(qfc[2], qfc[3], ahi[1], alo[1]);

    // prefetch next tile under the MFMAs below
    if (i < 7) load_tile(i + 1, qfn, gn);

    f32x4 acc[4];
#pragma unroll
    for (int nt = 0; nt < 4; ++nt) {
      const float bv = bias[nt];
      acc[nt] = (f32x4){bv, bv, bv, bv};
    }
#pragma unroll
    for (int ks = 0; ks < 2; ++ks) {
      const s16x8 ah = __builtin_bit_cast(s16x8, ahi[ks]);
      const s16x8 al = __builtin_bit_cast(s16x8, alo[ks]);
#pragma unroll
      for (int nt = 0; nt < 4; ++nt) {
        const s16x8 bh = __builtin_bit_cast(s16x8, sB[((ks * 8 + nt * 2 + 0) * 64) + l]);
        const s16x8 bl = __builtin_bit_cast(s16x8, sB[((ks * 8 + nt * 2 + 1) * 64) + l]);
        acc[nt] = __builtin_amdgcn_mfma_f32_16x16x32_bf16(ah, bh, acc[nt], 0, 0, 0);
        acc[nt] = __builtin_amdgcn_mfma_f32_16x16x32_bf16(al, bh, acc[nt], 0, 0, 0);
        acc[nt] = __builtin_amdgcn_mfma_f32_16x16x32_bf16(ah, bl, acc[nt], 0, 0, 0);
      }
    }

    // epilogue: rep = relu(feat@W1 + femb[idx] + bias) ; pool
    const float rw_all = rep ? rat1 : rat0;
#pragma unroll
    for (int e = 0; e < 4; ++e) {
      const int rr = m * 16 + lg * 4 + e;
      const float w = __shfl(rw_all, rr, 64);
#pragma unroll
      for (int nt = 0; nt < 4; ++nt) {
        const float repv = fmaxf(acc[nt][e] + gc[e * 4 + nt], 0.f);
        uacc[nt] = fmaf(w, repv, uacc[nt]);
        if (m == 3 && e == 2) trep[nt] = repv;   // row 50 = target (valid on lg==0)
      }
    }

    if (m == 3) {
      // finalize this batch
      const int bb = rep ? b1 : b0;
      float den = fabsf(rw_all);
#pragma unroll
      for (int s = 32; s >= 1; s >>= 1) den += __shfl_xor(den, s, 64);
#pragma unroll
      for (int nt = 0; nt < 4; ++nt) {
        uacc[nt] += __shfl_xor(uacc[nt], 16, 64);
        uacc[nt] += __shfl_xor(uacc[nt], 32, 64);
      }
      const float dinv = den + 1e-8f;
      const float usel = (lg == 0) ? uacc[0] : (lg == 1) ? uacc[1]
                       : (lg == 2) ? uacc[2] : uacc[3];
      user_vec[(size_t)bb * 64 + l] = usel / dinv;
      if (l < 16) {
        float* tp = target_rep + (size_t)bb * 64 + l;
        tp[0]  = trep[0];
        tp[16] = trep[1];
        tp[32] = trep[2];
        tp[48] = trep[3];
      }
#pragma unroll
      for (int nt = 0; nt < 4; ++nt) { uacc[nt] = 0.f; trep[nt] = 0.f; }
    }

    // cap scheduler pressure: no cross-tile hoisting bulges
    __builtin_amdgcn_sched_barrier(0);
  }
}

// ---------------- kernel C: rating MLP ----------------
__global__ __launch_bounds__(256) void mlp_k(
    const float* __restrict__ user_vec, const float* __restrict__ target_rep,
    const float* __restrict__ w1, const float* __restrict__ b1,
    const float* __restrict__ w2, const float* __restrict__ b2,
    const float* __restrict__ w3, const float* __restrict__ b3,
    float* __restrict__ out)
{
  __shared__ alignas(16) float s_w1[128 * 64];  // 32 KB
  __shared__ alignas(16) float s_w2[64 * 32];   //  8 KB
  __shared__ float s_w3[32];
  __shared__ alignas(16) float s_x[4][128];
  __shared__ alignas(16) float s_h1[4][64];
  const int tid = threadIdx.x;
  for (int i = tid; i < 128 * 64; i += 256) s_w1[i] = w1[i];
  for (int i = tid; i < 64 * 32;  i += 256) s_w2[i] = w2[i];
  if (tid < 32) s_w3[tid] = w3[tid];
  __syncthreads();

  const int t  = tid & 63;
  const int wv = tid >> 6;
  const int nwaves = gridDim.x << 2;
  const float b1t = b1[t];
  const float bb3 = b3[0];
  const int n2 = t & 31;
  const float b2n = b2[n2];
  for (int b = (blockIdx.x << 2) + wv; b < NB; b += nwaves) {
    s_x[wv][t]      = user_vec[(size_t)b * 64 + t];
    s_x[wv][64 + t] = target_rep[(size_t)b * 64 + t];
    float a0 = b1t, a1 = 0.f, a2 = 0.f, a3 = 0.f;
#pragma unroll
    for (int k4 = 0; k4 < 32; ++k4) {
      float4 x = *reinterpret_cast<const float4*>(&s_x[wv][k4 * 4]);
      a0 = fmaf(x.x, s_w1[(4 * k4 + 0) * 64 + t], a0);
      a1 = fmaf(x.y, s_w1[(4 * k4 + 1) * 64 + t], a1);
      a2 = fmaf(x.z, s_w1[(4 * k4 + 2) * 64 + t], a2);
      a3 = fmaf(x.w, s_w1[(4 * k4 + 3) * 64 + t], a3);
    }
    s_h1[wv][t] = fmaxf((a0 + a1) + (a2 + a3), 0.f);
    float c0 = b2n, c1 = 0.f, c2 = 0.f, c3 = 0.f;
#pragma unroll
    for (int k4 = 0; k4 < 16; ++k4) {
      float4 x = *reinterpret_cast<const float4*>(&s_h1[wv][k4 * 4]);
      c0 = fmaf(x.x, s_w2[(4 * k4 + 0) * 32 + n2], c0);
      c1 = fmaf(x.y, s_w2[(4 * k4 + 1) * 32 + n2], c1);
      c2 = fmaf(x.z, s_w2[(4 * k4 + 2) * 32 + n2], c2);
      c3 = fmaf(x.w, s_w2[(4 * k4 + 3) * 32 + n2], c3);
    }
    const float h2 = fmaxf((c0 + c1) + (c2 + c3), 0.f);
    float p = (t < 32) ? h2 * s_w3[n2] : 0.f;
#pragma unroll
    for (int m = 32; m >= 1; m >>= 1) p += __shfl_xor(p, m, 64);
    if (t == 0) out[b] = p + bb3;
  }
}

extern "C" void kernel_launch(void* const* d_in, const int* in_sizes, int n_in,
                              void* d_out, int out_size, void* d_ws, size_t ws_size,
                              hipStream_t stream) {
  const int*   hidx  = (const int*)  d_in[0];
  const float* hfeat = (const float*)d_in[1];
  const float* hrat  = (const float*)d_in[2];
  const int*   tidx  = (const int*)  d_in[3];
  const float* tfeat = (const float*)d_in[4];
  const float* table = (const float*)d_in[5];
  const float* fw    = (const float*)d_in[6];
  const float* fb    = (const float*)d_in[7];
  const float* w1    = (const float*)d_in[8];
  const float* b1    = (const float*)d_in[9];
  const float* w2    = (const float*)d_in[10];
  const float* b2    = (const float*)d_in[11];
  const float* w3    = (const float*)d_in[12];
  const float* b3    = (const float*)d_in[13];
  float* out = (float*)d_out;
  float* ws  = (float*)d_ws;
  unsigned* bfrag   = (unsigned*)ws;       // [0, 8192)
  float* femb       = ws + 16384;          // 6.4M floats
  float* user_vec   = ws + 8000000;
  float* target_rep = ws + 9048576;

  hipLaunchKernelGGL(wprep_k, dim3(32), dim3(256), 0, stream, fw, bfrag);
  hipLaunchKernelGGL(femb_k, dim3((NITEMS / 16 + 3) / 4), dim3(256), 0, stream,
                     table, bfrag, femb);
  hipLaunchKernelGGL(pool_mfma_k, dim3(2048), dim3(256), 0, stream,
                     hidx, hfeat, hrat, tidx, tfeat, femb, fb, bfrag,
                     user_vec, target_rep);
  hipLaunchKernelGGL(mlp_k, dim3(512), dim3(256), 0, stream,
                     user_vec, target_rep, w1, b1, w2, b2, w3, b3, out);
}

// Round 19
// 107.436 us; speedup vs baseline: 1.5249x; 1.0388x over previous
//
#include <hip/hip_runtime.h>
#include <hip/hip_bf16.h>

#define NB 16384
#define NH 50

typedef __attribute__((ext_vector_type(4))) float        f32x4;
typedef __attribute__((ext_vector_type(8))) short        s16x8;
typedef __attribute__((ext_vector_type(4))) unsigned int u32x4;

// ws layout (floats):
//   bfrag (u32) : [0, 8192)        32 KB  — W hi/lo bf16 MFMA fragments
//   user_vec    : [6400000, +1M)   4.2 MB
//   target_rep  : [7448576, +1M)   4.2 MB

__device__ __forceinline__ unsigned rne16(float x) {
  unsigned u = __float_as_uint(x);
  return (u + 0x7FFFu + ((u >> 16) & 1u)) >> 16;
}

__device__ __forceinline__ unsigned pk_bf16(float r0, float r1) {
  __hip_bfloat162 h = __float22bfloat162_rn(make_float2(r0, r1));  // v_cvt_pk_bf16_f32
  unsigned u;
  __builtin_memcpy(&u, &h, 4);
  return u;
}

// trunc-hi split: x = hi + r exactly (hi = upper-16 bits, bf16-representable);
// lo = rne(r).
__device__ __forceinline__ void cvt8t(const f32x4 a, const f32x4 b, u32x4& hi, u32x4& lo) {
  unsigned ha[8]; float r[8];
#pragma unroll
  for (int i = 0; i < 4; ++i) {
    const unsigned ua = __float_as_uint(a[i]) & 0xFFFF0000u;
    ha[i] = ua; r[i] = a[i] - __uint_as_float(ua);
  }
#pragma unroll
  for (int i = 0; i < 4; ++i) {
    const unsigned ub = __float_as_uint(b[i]) & 0xFFFF0000u;
    ha[4 + i] = ub; r[4 + i] = b[i] - __uint_as_float(ub);
  }
#pragma unroll
  for (int p = 0; p < 4; ++p) {
    hi[p] = ha[2 * p + 1] | (ha[2 * p] >> 16);   // elem 2p -> low16, 2p+1 -> high16
    lo[p] = pk_bf16(r[2 * p], r[2 * p + 1]);
  }
}

// ---------------- kernel W: build bf16 hi/lo B-fragments of fusion_w ----------------
// frag set f = (ks<<3)|(nt<<1)|sp ; lane l ; dword j : B[ks*32+(l>>4)*8+2j(+1)][nt*16+(l&15)]
__global__ __launch_bounds__(256) void wprep_k(const float* __restrict__ fw,
                                               unsigned* __restrict__ bfrag) {
  const int d = blockIdx.x * 256 + threadIdx.x;   // 0..8191
  const int j = d & 3, l = (d >> 2) & 63, f = d >> 8;
  const int sp = f & 1, nt = (f >> 1) & 3, ks = f >> 3;
  const int n  = nt * 16 + (l & 15);
  const int k0 = ks * 32 + (l >> 4) * 8 + 2 * j;
  const float w0 = fw[k0 * 64 + n], w1 = fw[(k0 + 1) * 64 + n];
  const unsigned h0 = rne16(w0), h1 = rne16(w1);
  unsigned dw;
  if (sp == 0) dw = h0 | (h1 << 16);
  else {
    const float r0 = w0 - __uint_as_float(h0 << 16);
    const float r1 = w1 - __uint_as_float(h1 << 16);
    dw = rne16(r0) | (rne16(r1) << 16);
  }
  bfrag[d] = dw;
}

// ---------------- kernel B: MFMA item-rep + pooling ----------------
// B in LDS + sched_barrier per tile (R14 discipline). Change vs R14:
// 2 waves/SIMD (256-reg cap, ample headroom) + 2-deep prefetch so the
// gather/stream issue->use distance (~2 tiles) exceeds HBM latency.
__global__ __launch_bounds__(256, 2) void pool_mfma_k(
    const int* __restrict__ hidx, const float* __restrict__ hfeat,
    const float* __restrict__ hrat, const int* __restrict__ tidx,
    const float* __restrict__ tfeat, const float* __restrict__ table,
    const float* __restrict__ fb, const unsigned* __restrict__ bfrag,
    float* __restrict__ user_vec, float* __restrict__ target_rep)
{
  __shared__ u32x4 sB[2048];   // 32 KB: frag f in 0..31, lane l: sB[f*64 + l]
  const int tid = threadIdx.x;
  {
    const u32x4* src = (const u32x4*)bfrag;
#pragma unroll
    for (int k = 0; k < 8; ++k) sB[tid + k * 256] = src[tid + k * 256];
  }

  const int l  = tid & 63;
  const int wv = tid >> 6;
  const int wave = (blockIdx.x << 2) + wv;          // 0..8191
  const int lm = l & 15, lg = l >> 4;
  const int b0 = wave, b1 = wave + 8192;

  // coalesced headers for BOTH batches
  const int r_l = (l < NH) ? l : (NH - 1);
  int idxv0 = hidx[(size_t)b0 * NH + r_l];
  int idxv1 = hidx[(size_t)b1 * NH + r_l];
  float rat0 = (l < NH) ? (hrat[(size_t)b0 * NH + l] - 3.0f) : 0.f;
  float rat1 = (l < NH) ? (hrat[(size_t)b1 * NH + l] - 3.0f) : 0.f;
  if (l == NH) { idxv0 = tidx[b0]; idxv1 = tidx[b1]; }   // lane 50 carries target

  float bias[4];
#pragma unroll
  for (int nt = 0; nt < 4; ++nt) bias[nt] = fb[nt * 16 + lm];

  __syncthreads();   // sB ready

  // tile i (i = rep*4 + m): load A-rows for 16x128 sub-tile into q[8]
  auto load_tile = [&](int i, f32x4* q) {
    const int rep = i >> 2, m = i & 3;
    const int bb  = rep ? b1 : b0;
    const int mi  = rep ? idxv1 : idxv0;
    const int r   = m * 16 + lm;
    const int sel = (r <= NH) ? r : (NH - 1);
    const int idxm = __shfl(mi, sel, 64);
    const float* fp = (r < NH) ? (hfeat + ((size_t)bb * NH + r) * 64)
                    : (r == NH) ? (tfeat + (size_t)bb * 64)
                                : (hfeat + ((size_t)bb * NH + (NH - 1)) * 64);
    const float* ep = table + (size_t)idxm * 64;
    q[0] = *(const f32x4*)(ep + lg * 8);
    q[1] = *(const f32x4*)(ep + lg * 8 + 4);
    q[2] = *(const f32x4*)(ep + 32 + lg * 8);
    q[3] = *(const f32x4*)(ep + 32 + lg * 8 + 4);
    q[4] = *(const f32x4*)(fp + lg * 8);
    q[5] = *(const f32x4*)(fp + lg * 8 + 4);
    q[6] = *(const f32x4*)(fp + 32 + lg * 8);
    q[7] = *(const f32x4*)(fp + 32 + lg * 8 + 4);
  };

  f32x4 qA[8], qB[8], qC[8];
  load_tile(0, qA);
  load_tile(1, qB);

  float uacc[4] = {0.f, 0.f, 0.f, 0.f};
  float trep[4] = {0.f, 0.f, 0.f, 0.f};

#pragma unroll
  for (int i = 0; i < 8; ++i) {
    const int rep = i >> 2, m = i & 3;
    // fully unrolled loop -> all buffer selections are compile-time
    f32x4* qc = (i % 3 == 0) ? qA : (i % 3 == 1) ? qB : qC;
    f32x4* qn = ((i + 2) % 3 == 0) ? qA : ((i + 2) % 3 == 1) ? qB : qC;

    // convert current tile (qc dies here)
    u32x4 ahi[4], alo[4];
    cvt8t(qc[0], qc[1], ahi[0], alo[0]);
    cvt8t(qc[2], qc[3], ahi[1], alo[1]);
    cvt8t(qc[4], qc[5], ahi[2], alo[2]);
    cvt8t(qc[6], qc[7], ahi[3], alo[3]);

    // prefetch tile i+2: issue->use distance ~2 full tile bodies
    if (i < 6) load_tile(i + 2, qn);

    f32x4 acc[4];
#pragma unroll
    for (int nt = 0; nt < 4; ++nt) {
      const float bv = bias[nt];
      acc[nt] = (f32x4){bv, bv, bv, bv};
    }
#pragma unroll
    for (int ks = 0; ks < 4; ++ks) {
      const s16x8 ah = __builtin_bit_cast(s16x8, ahi[ks]);
      const s16x8 al = __builtin_bit_cast(s16x8, alo[ks]);
#pragma unroll
      for (int nt = 0; nt < 4; ++nt) {
        const s16x8 bh = __builtin_bit_cast(s16x8, sB[((ks * 8 + nt * 2 + 0) * 64) + l]);
        const s16x8 bl = __builtin_bit_cast(s16x8, sB[((ks * 8 + nt * 2 + 1) * 64) + l]);
        acc[nt] = __builtin_amdgcn_mfma_f32_16x16x32_bf16(ah, bh, acc[nt], 0, 0, 0);
        acc[nt] = __builtin_amdgcn_mfma_f32_16x16x32_bf16(al, bh, acc[nt], 0, 0, 0);
        acc[nt] = __builtin_amdgcn_mfma_f32_16x16x32_bf16(ah, bl, acc[nt], 0, 0, 0);
      }
    }

    // epilogue: relu + weighted pooling ; C layout: col=lm+16nt, row=m*16+lg*4+e
    const float rw_all = rep ? rat1 : rat0;
#pragma unroll
    for (int e = 0; e < 4; ++e) {
      const int rr = m * 16 + lg * 4 + e;
      const float w = __shfl(rw_all, rr, 64);
#pragma unroll
      for (int nt = 0; nt < 4; ++nt) {
        const float repv = fmaxf(acc[nt][e], 0.f);
        uacc[nt] = fmaf(w, repv, uacc[nt]);
        if (m == 3 && e == 2) trep[nt] = repv;   // row 50 = target (valid on lg==0)
      }
    }

    if (m == 3) {
      // finalize this batch
      const int bb = rep ? b1 : b0;
      float den = fabsf(rw_all);
#pragma unroll
      for (int s = 32; s >= 1; s >>= 1) den += __shfl_xor(den, s, 64);
#pragma unroll
      for (int nt = 0; nt < 4; ++nt) {
        uacc[nt] += __shfl_xor(uacc[nt], 16, 64);
        uacc[nt] += __shfl_xor(uacc[nt], 32, 64);
      }
      const float dinv = den + 1e-8f;
      const float usel = (lg == 0) ? uacc[0] : (lg == 1) ? uacc[1]
                       : (lg == 2) ? uacc[2] : uacc[3];
      user_vec[(size_t)bb * 64 + l] = usel / dinv;
      if (l < 16) {
        float* tp = target_rep + (size_t)bb * 64 + l;
        tp[0]  = trep[0];
        tp[16] = trep[1];
        tp[32] = trep[2];
        tp[48] = trep[3];
      }
#pragma unroll
      for (int nt = 0; nt < 4; ++nt) { uacc[nt] = 0.f; trep[nt] = 0.f; }
    }

    // cap scheduler pressure: no cross-tile hoisting bulges
    __builtin_amdgcn_sched_barrier(0);
  }
}

// ---------------- kernel C: rating MLP ----------------
__global__ __launch_bounds__(256) void mlp_k(
    const float* __restrict__ user_vec, const float* __restrict__ target_rep,
    const float* __restrict__ w1, const float* __restrict__ b1,
    const float* __restrict__ w2, const float* __restrict__ b2,
    const float* __restrict__ w3, const float* __restrict__ b3,
    float* __restrict__ out)
{
  __shared__ alignas(16) float s_w1[128 * 64];  // 32 KB
  __shared__ alignas(16) float s_w2[64 * 32];   //  8 KB
  __shared__ float s_w3[32];
  __shared__ alignas(16) float s_x[4][128];
  __shared__ alignas(16) float s_h1[4][64];
  const int tid = threadIdx.x;
  for (int i = tid; i < 128 * 64; i += 256) s_w1[i] = w1[i];
  for (int i = tid; i < 64 * 32;  i += 256) s_w2[i] = w2[i];
  if (tid < 32) s_w3[tid] = w3[tid];
  __syncthreads();

  const int t  = tid & 63;
  const int wv = tid >> 6;
  const int nwaves = gridDim.x << 2;
  const float b1t = b1[t];
  const float bb3 = b3[0];
  const int n2 = t & 31;
  const float b2n = b2[n2];
  for (int b = (blockIdx.x << 2) + wv; b < NB; b += nwaves) {
    s_x[wv][t]      = user_vec[(size_t)b * 64 + t];
    s_x[wv][64 + t] = target_rep[(size_t)b * 64 + t];
    float a0 = b1t, a1 = 0.f, a2 = 0.f, a3 = 0.f;
#pragma unroll
    for (int k4 = 0; k4 < 32; ++k4) {
      float4 x = *reinterpret_cast<const float4*>(&s_x[wv][k4 * 4]);
      a0 = fmaf(x.x, s_w1[(4 * k4 + 0) * 64 + t], a0);
      a1 = fmaf(x.y, s_w1[(4 * k4 + 1) * 64 + t], a1);
      a2 = fmaf(x.z, s_w1[(4 * k4 + 2) * 64 + t], a2);
      a3 = fmaf(x.w, s_w1[(4 * k4 + 3) * 64 + t], a3);
    }
    s_h1[wv][t] = fmaxf((a0 + a1) + (a2 + a3), 0.f);
    float c0 = b2n, c1 = 0.f, c2 = 0.f, c3 = 0.f;
#pragma unroll
    for (int k4 = 0; k4 < 16; ++k4) {
      float4 x = *reinterpret_cast<const float4*>(&s_h1[wv][k4 * 4]);
      c0 = fmaf(x.x, s_w2[(4 * k4 + 0) * 32 + n2], c0);
      c1 = fmaf(x.y, s_w2[(4 * k4 + 1) * 32 + n2], c1);
      c2 = fmaf(x.z, s_w2[(4 * k4 + 2) * 32 + n2], c2);
      c3 = fmaf(x.w, s_w2[(4 * k4 + 3) * 32 + n2], c3);
    }
    const float h2 = fmaxf((c0 + c1) + (c2 + c3), 0.f);
    float p = (t < 32) ? h2 * s_w3[n2] : 0.f;
#pragma unroll
    for (int m = 32; m >= 1; m >>= 1) p += __shfl_xor(p, m, 64);
    if (t == 0) out[b] = p + bb3;
  }
}

extern "C" void kernel_launch(void* const* d_in, const int* in_sizes, int n_in,
                              void* d_out, int out_size, void* d_ws, size_t ws_size,
                              hipStream_t stream) {
  const int*   hidx  = (const int*)  d_in[0];
  const float* hfeat = (const float*)d_in[1];
  const float* hrat  = (const float*)d_in[2];
  const int*   tidx  = (const int*)  d_in[3];
  const float* tfeat = (const float*)d_in[4];
  const float* table = (const float*)d_in[5];
  const float* fw    = (const float*)d_in[6];
  const float* fb    = (const float*)d_in[7];
  const float* w1    = (const float*)d_in[8];
  const float* b1    = (const float*)d_in[9];
  const float* w2    = (const float*)d_in[10];
  const float* b2    = (const float*)d_in[11];
  const float* w3    = (const float*)d_in[12];
  const float* b3    = (const float*)d_in[13];
  float* out = (float*)d_out;
  float* ws  = (float*)d_ws;
  unsigned* bfrag   = (unsigned*)ws;      // 8192 dwords
  float* user_vec   = ws + 6400000;
  float* target_rep = ws + 7448576;

  hipLaunchKernelGGL(wprep_k, dim3(32), dim3(256), 0, stream, fw, bfrag);
  hipLaunchKernelGGL(pool_mfma_k, dim3(2048), dim3(256), 0, stream,
                     hidx, hfeat, hrat, tidx, tfeat, table, fb, bfrag,
                     user_vec, target_rep);
  hipLaunchKernelGGL(mlp_k, dim3(512), dim3(256), 0, stream,
                     user_vec, target_rep, w1, b1, w2, b2, w3, b3, out);
}

// Round 20
// 99.581 us; speedup vs baseline: 1.6452x; 1.0789x over previous
//
#include <hip/hip_runtime.h>
#include <hip/hip_bf16.h>

#define NB 16384
#define NH 50

typedef __attribute__((ext_vector_type(4))) float        f32x4;
typedef __attribute__((ext_vector_type(8))) short        s16x8;
typedef __attribute__((ext_vector_type(4))) unsigned int u32x4;

// ws layout (floats):
//   bfrag (u32) : [0, 8192)        32 KB  — W hi/lo bf16 MFMA fragments
//   user_vec    : [6400000, +1M)   4.2 MB
//   target_rep  : [7448576, +1M)   4.2 MB

__device__ __forceinline__ unsigned rne16(float x) {
  unsigned u = __float_as_uint(x);
  return (u + 0x7FFFu + ((u >> 16) & 1u)) >> 16;
}

__device__ __forceinline__ unsigned pk_bf16(float r0, float r1) {
  __hip_bfloat162 h = __float22bfloat162_rn(make_float2(r0, r1));  // v_cvt_pk_bf16_f32
  unsigned u;
  __builtin_memcpy(&u, &h, 4);
  return u;
}

// trunc-hi split: x = hi + r exactly (hi = upper-16 bits, bf16-representable);
// lo = rne(r).
__device__ __forceinline__ void cvt8t(const f32x4 a, const f32x4 b, u32x4& hi, u32x4& lo) {
  unsigned ha[8]; float r[8];
#pragma unroll
  for (int i = 0; i < 4; ++i) {
    const unsigned ua = __float_as_uint(a[i]) & 0xFFFF0000u;
    ha[i] = ua; r[i] = a[i] - __uint_as_float(ua);
  }
#pragma unroll
  for (int i = 0; i < 4; ++i) {
    const unsigned ub = __float_as_uint(b[i]) & 0xFFFF0000u;
    ha[4 + i] = ub; r[4 + i] = b[i] - __uint_as_float(ub);
  }
#pragma unroll
  for (int p = 0; p < 4; ++p) {
    hi[p] = ha[2 * p + 1] | (ha[2 * p] >> 16);   // elem 2p -> low16, 2p+1 -> high16
    lo[p] = pk_bf16(r[2 * p], r[2 * p + 1]);
  }
}

// ---------------- kernel W: build bf16 hi/lo B-fragments of fusion_w ----------------
// frag set f = (ks<<3)|(nt<<1)|sp ; lane l ; dword j : B[ks*32+(l>>4)*8+2j(+1)][nt*16+(l&15)]
__global__ __launch_bounds__(256) void wprep_k(const float* __restrict__ fw,
                                               unsigned* __restrict__ bfrag) {
  const int d = blockIdx.x * 256 + threadIdx.x;   // 0..8191
  const int j = d & 3, l = (d >> 2) & 63, f = d >> 8;
  const int sp = f & 1, nt = (f >> 1) & 3, ks = f >> 3;
  const int n  = nt * 16 + (l & 15);
  const int k0 = ks * 32 + (l >> 4) * 8 + 2 * j;
  const float w0 = fw[k0 * 64 + n], w1 = fw[(k0 + 1) * 64 + n];
  const unsigned h0 = rne16(w0), h1 = rne16(w1);
  unsigned dw;
  if (sp == 0) dw = h0 | (h1 << 16);
  else {
    const float r0 = w0 - __uint_as_float(h0 << 16);
    const float r1 = w1 - __uint_as_float(h1 << 16);
    dw = rne16(r0) | (rne16(r1) << 16);
  }
  bfrag[d] = dw;
}

// ---------------- kernel B: MFMA item-rep + pooling ----------------
// B in LDS + 3 waves/SIMD + sched_barrier per tile (spill-free) +
// 1-deep qA/qB prefetch pipeline. Measured optimum of the config matrix
// (R8..R19): every neighboring config (4/SIMD, 2-deep, 2-batch fusion,
// K=64 restructure, prepacked table) is worse via spills or added latency.
__global__ __launch_bounds__(256, 3) void pool_mfma_k(
    const int* __restrict__ hidx, const float* __restrict__ hfeat,
    const float* __restrict__ hrat, const int* __restrict__ tidx,
    const float* __restrict__ tfeat, const float* __restrict__ table,
    const float* __restrict__ fb, const unsigned* __restrict__ bfrag,
    float* __restrict__ user_vec, float* __restrict__ target_rep)
{
  __shared__ u32x4 sB[2048];   // 32 KB: frag f in 0..31, lane l: sB[f*64 + l]
  const int tid = threadIdx.x;
  {
    const u32x4* src = (const u32x4*)bfrag;
#pragma unroll
    for (int k = 0; k < 8; ++k) sB[tid + k * 256] = src[tid + k * 256];
  }

  const int l  = tid & 63;
  const int wv = tid >> 6;
  const int wave = (blockIdx.x << 2) + wv;          // 0..8191
  const int lm = l & 15, lg = l >> 4;
  const int b0 = wave, b1 = wave + 8192;

  // coalesced headers for BOTH batches
  const int r_l = (l < NH) ? l : (NH - 1);
  int idxv0 = hidx[(size_t)b0 * NH + r_l];
  int idxv1 = hidx[(size_t)b1 * NH + r_l];
  float rat0 = (l < NH) ? (hrat[(size_t)b0 * NH + l] - 3.0f) : 0.f;
  float rat1 = (l < NH) ? (hrat[(size_t)b1 * NH + l] - 3.0f) : 0.f;
  if (l == NH) { idxv0 = tidx[b0]; idxv1 = tidx[b1]; }   // lane 50 carries target

  float bias[4];
#pragma unroll
  for (int nt = 0; nt < 4; ++nt) bias[nt] = fb[nt * 16 + lm];

  __syncthreads();   // sB ready

  // tile i (i = rep*4 + m): load A-rows for 16x128 sub-tile into q[8]
  auto load_tile = [&](int i, f32x4* q) {
    const int rep = i >> 2, m = i & 3;
    const int bb  = rep ? b1 : b0;
    const int mi  = rep ? idxv1 : idxv0;
    const int r   = m * 16 + lm;
    const int sel = (r <= NH) ? r : (NH - 1);
    const int idxm = __shfl(mi, sel, 64);
    const float* fp = (r < NH) ? (hfeat + ((size_t)bb * NH + r) * 64)
                    : (r == NH) ? (tfeat + (size_t)bb * 64)
                                : (hfeat + ((size_t)bb * NH + (NH - 1)) * 64);
    const float* ep = table + (size_t)idxm * 64;
    q[0] = *(const f32x4*)(ep + lg * 8);
    q[1] = *(const f32x4*)(ep + lg * 8 + 4);
    q[2] = *(const f32x4*)(ep + 32 + lg * 8);
    q[3] = *(const f32x4*)(ep + 32 + lg * 8 + 4);
    q[4] = *(const f32x4*)(fp + lg * 8);
    q[5] = *(const f32x4*)(fp + lg * 8 + 4);
    q[6] = *(const f32x4*)(fp + 32 + lg * 8);
    q[7] = *(const f32x4*)(fp + 32 + lg * 8 + 4);
  };

  f32x4 qA[8], qB[8];
  load_tile(0, qA);

  float uacc[4] = {0.f, 0.f, 0.f, 0.f};
  float trep[4] = {0.f, 0.f, 0.f, 0.f};

#pragma unroll
  for (int i = 0; i < 8; ++i) {
    const int rep = i >> 2, m = i & 3;
    f32x4* qc = (i & 1) ? qB : qA;
    f32x4* qn = (i & 1) ? qA : qB;

    // convert current tile (qc dies here)
    u32x4 ahi[4], alo[4];
    cvt8t(qc[0], qc[1], ahi[0], alo[0]);
    cvt8t(qc[2], qc[3], ahi[1], alo[1]);
    cvt8t(qc[4], qc[5], ahi[2], alo[2]);
    cvt8t(qc[6], qc[7], ahi[3], alo[3]);

    // prefetch next tile; its s_waitcnt lands at tile i+1's cvt
    if (i < 7) load_tile(i + 1, qn);

    f32x4 acc[4];
#pragma unroll
    for (int nt = 0; nt < 4; ++nt) {
      const float bv = bias[nt];
      acc[nt] = (f32x4){bv, bv, bv, bv};
    }
#pragma unroll
    for (int ks = 0; ks < 4; ++ks) {
      const s16x8 ah = __builtin_bit_cast(s16x8, ahi[ks]);
      const s16x8 al = __builtin_bit_cast(s16x8, alo[ks]);
#pragma unroll
      for (int nt = 0; nt < 4; ++nt) {
        const s16x8 bh = __builtin_bit_cast(s16x8, sB[((ks * 8 + nt * 2 + 0) * 64) + l]);
        const s16x8 bl = __builtin_bit_cast(s16x8, sB[((ks * 8 + nt * 2 + 1) * 64) + l]);
        acc[nt] = __builtin_amdgcn_mfma_f32_16x16x32_bf16(ah, bh, acc[nt], 0, 0, 0);
        acc[nt] = __builtin_amdgcn_mfma_f32_16x16x32_bf16(al, bh, acc[nt], 0, 0, 0);
        acc[nt] = __builtin_amdgcn_mfma_f32_16x16x32_bf16(ah, bl, acc[nt], 0, 0, 0);
      }
    }

    // epilogue: relu + weighted pooling ; C layout: col=lm+16nt, row=m*16+lg*4+e
    const float rw_all = rep ? rat1 : rat0;
#pragma unroll
    for (int e = 0; e < 4; ++e) {
      const int rr = m * 16 + lg * 4 + e;
      const float w = __shfl(rw_all, rr, 64);
#pragma unroll
      for (int nt = 0; nt < 4; ++nt) {
        const float repv = fmaxf(acc[nt][e], 0.f);
        uacc[nt] = fmaf(w, repv, uacc[nt]);
        if (m == 3 && e == 2) trep[nt] = repv;   // row 50 = target (valid on lg==0)
      }
    }

    if (m == 3) {
      // finalize this batch
      const int bb = rep ? b1 : b0;
      float den = fabsf(rw_all);
#pragma unroll
      for (int s = 32; s >= 1; s >>= 1) den += __shfl_xor(den, s, 64);
#pragma unroll
      for (int nt = 0; nt < 4; ++nt) {
        uacc[nt] += __shfl_xor(uacc[nt], 16, 64);
        uacc[nt] += __shfl_xor(uacc[nt], 32, 64);
      }
      const float dinv = den + 1e-8f;
      const float usel = (lg == 0) ? uacc[0] : (lg == 1) ? uacc[1]
                       : (lg == 2) ? uacc[2] : uacc[3];
      user_vec[(size_t)bb * 64 + l] = usel / dinv;
      if (l < 16) {
        float* tp = target_rep + (size_t)bb * 64 + l;
        tp[0]  = trep[0];
        tp[16] = trep[1];
        tp[32] = trep[2];
        tp[48] = trep[3];
      }
#pragma unroll
      for (int nt = 0; nt < 4; ++nt) { uacc[nt] = 0.f; trep[nt] = 0.f; }
    }

    // cap scheduler pressure: no cross-tile hoisting bulges
    __builtin_amdgcn_sched_barrier(0);
  }
}

// ---------------- kernel C: rating MLP ----------------
__global__ __launch_bounds__(256) void mlp_k(
    const float* __restrict__ user_vec, const float* __restrict__ target_rep,
    const float* __restrict__ w1, const float* __restrict__ b1,
    const float* __restrict__ w2, const float* __restrict__ b2,
    const float* __restrict__ w3, const float* __restrict__ b3,
    float* __restrict__ out)
{
  __shared__ alignas(16) float s_w1[128 * 64];  // 32 KB
  __shared__ alignas(16) float s_w2[64 * 32];   //  8 KB
  __shared__ float s_w3[32];
  __shared__ alignas(16) float s_x[4][128];
  __shared__ alignas(16) float s_h1[4][64];
  const int tid = threadIdx.x;
  for (int i = tid; i < 128 * 64; i += 256) s_w1[i] = w1[i];
  for (int i = tid; i < 64 * 32;  i += 256) s_w2[i] = w2[i];
  if (tid < 32) s_w3[tid] = w3[tid];
  __syncthreads();

  const int t  = tid & 63;
  const int wv = tid >> 6;
  const int nwaves = gridDim.x << 2;
  const float b1t = b1[t];
  const float bb3 = b3[0];
  const int n2 = t & 31;
  const float b2n = b2[n2];
  for (int b = (blockIdx.x << 2) + wv; b < NB; b += nwaves) {
    s_x[wv][t]      = user_vec[(size_t)b * 64 + t];
    s_x[wv][64 + t] = target_rep[(size_t)b * 64 + t];
    float a0 = b1t, a1 = 0.f, a2 = 0.f, a3 = 0.f;
#pragma unroll
    for (int k4 = 0; k4 < 32; ++k4) {
      float4 x = *reinterpret_cast<const float4*>(&s_x[wv][k4 * 4]);
      a0 = fmaf(x.x, s_w1[(4 * k4 + 0) * 64 + t], a0);
      a1 = fmaf(x.y, s_w1[(4 * k4 + 1) * 64 + t], a1);
      a2 = fmaf(x.z, s_w1[(4 * k4 + 2) * 64 + t], a2);
      a3 = fmaf(x.w, s_w1[(4 * k4 + 3) * 64 + t], a3);
    }
    s_h1[wv][t] = fmaxf((a0 + a1) + (a2 + a3), 0.f);
    float c0 = b2n, c1 = 0.f, c2 = 0.f, c3 = 0.f;
#pragma unroll
    for (int k4 = 0; k4 < 16; ++k4) {
      float4 x = *reinterpret_cast<const float4*>(&s_h1[wv][k4 * 4]);
      c0 = fmaf(x.x, s_w2[(4 * k4 + 0) * 32 + n2], c0);
      c1 = fmaf(x.y, s_w2[(4 * k4 + 1) * 32 + n2], c1);
      c2 = fmaf(x.z, s_w2[(4 * k4 + 2) * 32 + n2], c2);
      c3 = fmaf(x.w, s_w2[(4 * k4 + 3) * 32 + n2], c3);
    }
    const float h2 = fmaxf((c0 + c1) + (c2 + c3), 0.f);
    float p = (t < 32) ? h2 * s_w3[n2] : 0.f;
#pragma unroll
    for (int m = 32; m >= 1; m >>= 1) p += __shfl_xor(p, m, 64);
    if (t == 0) out[b] = p + bb3;
  }
}

extern "C" void kernel_launch(void* const* d_in, const int* in_sizes, int n_in,
                              void* d_out, int out_size, void* d_ws, size_t ws_size,
                              hipStream_t stream) {
  const int*   hidx  = (const int*)  d_in[0];
  const float* hfeat = (const float*)d_in[1];
  const float* hrat  = (const float*)d_in[2];
  const int*   tidx  = (const int*)  d_in[3];
  const float* tfeat = (const float*)d_in[4];
  const float* table = (const float*)d_in[5];
  const float* fw    = (const float*)d_in[6];
  const float* fb    = (const float*)d_in[7];
  const float* w1    = (const float*)d_in[8];
  const float* b1    = (const float*)d_in[9];
  const float* w2    = (const float*)d_in[10];
  const float* b2    = (const float*)d_in[11];
  const float* w3    = (const float*)d_in[12];
  const float* b3    = (const float*)d_in[13];
  float* out = (float*)d_out;
  float* ws  = (float*)d_ws;
  unsigned* bfrag   = (unsigned*)ws;      // 8192 dwords
  float* user_vec   = ws + 6400000;
  float* target_rep = ws + 7448576;

  hipLaunchKernelGGL(wprep_k, dim3(32), dim3(256), 0, stream, fw, bfrag);
  hipLaunchKernelGGL(pool_mfma_k, dim3(2048), dim3(256), 0, stream,
                     hidx, hfeat, hrat, tidx, tfeat, table, fb, bfrag,
                     user_vec, target_rep);
  hipLaunchKernelGGL(mlp_k, dim3(512), dim3(256), 0, stream,
                     user_vec, target_rep, w1, b1, w2, b2, w3, b3, out);
}